// Round 3
// baseline (777.176 us; speedup 1.0000x reference)
//
#include <hip/hip_runtime.h>

// out[n,o] = sum_i x[n,i]*W[o,i] + b[o]
// x: 524288x128 fp32, W: 128x128 fp32 (row-major [o][i]), b: 128 fp32, out: 524288x128 fp32
//
// Memory-bound: ~536 MB mandatory HBM traffic -> ~85us floor at 6.3 TB/s.
// v2: W in LDS (B-fragment layout), freed registers -> 4 waves/SIMD.
// v3: depth-2 x prefetch -> NEUTRAL. MLP was never the limit (128KB/CU in
//     flight vs ~9KB BW-delay product). Latency hiding is TLP-limited.
// v4: VGPR <= 64 for 8 waves/SIMD (occupancy quantizes at 64/128/256):
//     - drop prefetch buffers (neutral anyway)
//     - bias folded into acc INIT (acc[t] = splat(b[col]); kills 32 adds)
//     - stage x one 32-k chunk (2 float4) at a time
//     512-thr blocks keep LDS at 4x32KB=128KB/CU <= 160KB at 8 waves/SIMD.

typedef __fp16   fp16x2   __attribute__((ext_vector_type(2)));  // cvt_pkrtz result
typedef _Float16 half8_t  __attribute__((ext_vector_type(8)));  // MFMA A/B operand
typedef float    float4_t __attribute__((ext_vector_type(4)));

constexpr int BATCH = 524288;
constexpr int K = 128;
constexpr int N = 128;
constexpr int GRID = 2048;
constexpr int WAVES_PER_BLOCK = 8;
constexpr int TILES_PER_WAVE = 2;   // 2048 blk * 8 waves * 2 tiles * 16 rows = 524288

__global__ __launch_bounds__(512, 8)
void linear_mfma_kernel(const float* __restrict__ x,
                        const float* __restrict__ W,
                        const float* __restrict__ bias,
                        float* __restrict__ out)
{
    // B-fragment store: slot (t*4 + c)*64 + lane holds the half8
    //   W[o = t*16 + (lane&15)][k = c*32 + (lane>>4)*8 .. +7]
    // Hot-loop read: lane i reads slot base+i -> contiguous 16B/lane, conflict-free.
    __shared__ half8_t lds_w[2048];   // 32 KB

    const int tid  = threadIdx.x;
    const int lane = tid & 63;
    const int wave = tid >> 6;
    const int l15  = lane & 15;   // A: m-row / B: o-col / C: col
    const int quad = lane >> 4;   // A,B: k-subchunk / C: row-quad

    // ---- one-time W fragment fill (coalesced global reads) ----
#pragma unroll
    for (int s = 0; s < 4; ++s) {
        const int g   = tid + s * 512;       // octet id, 0..2047
        const int o   = g >> 4;              // W row
        const int idx = g & 15;
        const int c   = idx >> 2;            // k-chunk of 32
        const int q   = idx & 3;             // k-subchunk of 8
        const float* wp = W + (size_t)o * K + c * 32 + q * 8;
        float4_t w0 = *(const float4_t*)(wp);
        float4_t w1 = *(const float4_t*)(wp + 4);
        union { half8_t v; fp16x2 h[4]; } u;
        u.h[0] = __builtin_amdgcn_cvt_pkrtz(w0.x, w0.y);
        u.h[1] = __builtin_amdgcn_cvt_pkrtz(w0.z, w0.w);
        u.h[2] = __builtin_amdgcn_cvt_pkrtz(w1.x, w1.y);
        u.h[3] = __builtin_amdgcn_cvt_pkrtz(w1.z, w1.w);
        const int t   = o >> 4;
        const int r15 = o & 15;
        lds_w[(t * 4 + c) * 64 + q * 16 + r15] = u.v;
    }

    // bias per lane per o-tile: col = t*16 + l15 (folded into acc init below)
    float bv[8];
#pragma unroll
    for (int t = 0; t < 8; ++t) bv[t] = bias[t * 16 + l15];

    __syncthreads();

    const int gw = blockIdx.x * WAVES_PER_BLOCK + wave;   // global wave id

#pragma unroll 1
    for (int it = 0; it < TILES_PER_WAVE; ++it) {
        const int m0 = (gw * TILES_PER_WAVE + it) * 16;
        const float* xp = x + (size_t)(m0 + l15) * K + quad * 8;

        // bias folded into accumulator init: acc[t][r] starts at b[t*16+l15]
        float4_t acc[8];
#pragma unroll
        for (int t = 0; t < 8; ++t) {
            acc[t][0] = bv[t]; acc[t][1] = bv[t];
            acc[t][2] = bv[t]; acc[t][3] = bv[t];
        }

#pragma unroll
        for (int c = 0; c < 4; ++c) {
            float4_t a0 = *(const float4_t*)(xp + c * 32);
            float4_t a1 = *(const float4_t*)(xp + c * 32 + 4);
            union { half8_t v; fp16x2 h[4]; } ua;
            ua.h[0] = __builtin_amdgcn_cvt_pkrtz(a0.x, a0.y);
            ua.h[1] = __builtin_amdgcn_cvt_pkrtz(a0.z, a0.w);
            ua.h[2] = __builtin_amdgcn_cvt_pkrtz(a1.x, a1.y);
            ua.h[3] = __builtin_amdgcn_cvt_pkrtz(a1.z, a1.w);
#pragma unroll
            for (int t = 0; t < 8; ++t) {
                half8_t bf = lds_w[(t * 4 + c) * 64 + lane];
                acc[t] = __builtin_amdgcn_mfma_f32_16x16x32_f16(ua.v, bf, acc[t], 0, 0, 0);
            }
        }

        // C/D layout: row = quad*4 + r, col = t*16 + l15
        float* op = out + (size_t)(m0 + quad * 4) * N + l15;
#pragma unroll
        for (int t = 0; t < 8; ++t) {
#pragma unroll
            for (int r = 0; r < 4; ++r) {
                op[(size_t)r * N + t * 16] = acc[t][r];
            }
        }
    }
}

extern "C" void kernel_launch(void* const* d_in, const int* in_sizes, int n_in,
                              void* d_out, int out_size, void* d_ws, size_t ws_size,
                              hipStream_t stream) {
    const float* x = (const float*)d_in[0];
    const float* W = (const float*)d_in[1];
    const float* b = (const float*)d_in[2];
    float* out = (float*)d_out;
    linear_mfma_kernel<<<GRID, 512, 0, stream>>>(x, W, b, out);
}

// Round 4
// 525.331 us; speedup vs baseline: 1.4794x; 1.4794x over previous
//
#include <hip/hip_runtime.h>

// out[n,o] = sum_i x[n,i]*W[o,i] + b[o]
// x: 524288x128 fp32, W: 128x128 fp32 (row-major [o][i]), b: 128 fp32, out: 524288x128 fp32
//
// Memory-bound: ~536 MB mandatory HBM traffic -> ~85us floor at 6.3 TB/s.
// v2: W in LDS (B-frag layout) -> 4 waves/SIMD, ~140us kernel.
// v3: depth-2 x prefetch -> NEUTRAL (MLP never the limit).
// v4: launch_bounds(512,8) with 32-reg acc -> 32 arch VGPRs, scratch spills
//     (+613MB sym. FETCH/WRITE bloat), 481us. Occupancy mechanism confirmed
//     (78%) but acc footprint must shrink to fit the 64-reg budget.
// v5: mfma_f32_32x32x16_f16, N split across waves: 32x32 tile/wave ->
//     acc=16 regs, bias=1 reg (col fixed per lane), ~50 total. 8 waves/SIMD
//     with NO spills. Stores become 2x128B full lines per instruction.

typedef __fp16   fp16x2   __attribute__((ext_vector_type(2)));  // cvt_pkrtz result
typedef _Float16 half8_t  __attribute__((ext_vector_type(8)));  // MFMA A/B operand
typedef float    float4_t __attribute__((ext_vector_type(4)));
typedef float    f32x16   __attribute__((ext_vector_type(16))); // MFMA C/D

constexpr int K = 128;
constexpr int N = 128;
constexpr int GRID = 2048;
constexpr int ITERS = 4;   // 64-row slabs per block -> 256 rows/block

__global__ __launch_bounds__(512, 8)
void linear_mfma_kernel(const float* __restrict__ x,
                        const float* __restrict__ W,
                        const float* __restrict__ bias,
                        float* __restrict__ out)
{
    // B-fragment layout for mfma_f32_32x32x16_f16, per col-group g (32 W rows):
    //   slot g*512 + c*64 + lane  holds  W[o = g*32 + (lane&31)][k = c*16 + (lane>>5)*8 .. +7]
    // Hot-loop read: lane i reads slot base+i -> contiguous 16B/lane, conflict-free.
    __shared__ half8_t lds_w[2048];   // 32 KB

    const int tid    = threadIdx.x;
    const int lane   = tid & 63;
    const int wave   = tid >> 6;
    const int l31    = lane & 31;   // A: m-row / B: o-col / C: col
    const int kh     = lane >> 5;   // A,B: k-half / C: row offset *4
    const int colgrp = wave & 3;    // which 32 output cols
    const int rowgrp = wave >> 2;   // which 32 rows within the 64-row slab

    // ---- one-time W fill: lds index = tid directly (conflict-free LDS writes;
    // scattered global reads hit the 64KB L2/L3-resident W, negligible) ----
#pragma unroll
    for (int s = 0; s < 4; ++s) {
        const int idx = tid + s * 512;
        const int cg  = idx >> 9;          // col-group
        const int c   = (idx >> 6) & 7;    // k-chunk of 16
        const int hf  = (idx >> 5) & 1;    // k-half of 8
        const int o5  = idx & 31;          // col within group
        const float* wp = W + (size_t)(cg * 32 + o5) * K + (c * 2 + hf) * 8;
        float4_t w0 = *(const float4_t*)(wp);
        float4_t w1 = *(const float4_t*)(wp + 4);
        union { half8_t v; fp16x2 h[4]; } u;
        u.h[0] = __builtin_amdgcn_cvt_pkrtz(w0.x, w0.y);
        u.h[1] = __builtin_amdgcn_cvt_pkrtz(w0.z, w0.w);
        u.h[2] = __builtin_amdgcn_cvt_pkrtz(w1.x, w1.y);
        u.h[3] = __builtin_amdgcn_cvt_pkrtz(w1.z, w1.w);
        lds_w[idx] = u.v;
    }

    // C/D col = colgrp*32 + (lane&31), identical for all 16 acc regs -> 1 bias reg
    const float bv = bias[colgrp * 32 + l31];

    __syncthreads();

#pragma unroll 1
    for (int it = 0; it < ITERS; ++it) {
        const int m0 = (blockIdx.x * ITERS + it) * 64 + rowgrp * 32;

        // Opaque zero per iteration: keeps the 8 ds_read_b128 inside the loop
        // (LICM would hoist 32 regs of W fragments and blow the budget).
        int zoff = 0;
        asm volatile("" : "+v"(zoff));
        const half8_t* wf = lds_w + colgrp * 512 + zoff;

        const float* xp = x + (size_t)(m0 + l31) * K + kh * 8;

        f32x16 acc;
#pragma unroll
        for (int r = 0; r < 16; ++r) acc[r] = bv;   // bias folded into init

#pragma unroll
        for (int c = 0; c < 8; ++c) {
            float4_t a0 = *(const float4_t*)(xp + c * 16);
            float4_t a1 = *(const float4_t*)(xp + c * 16 + 4);
            union { half8_t v; fp16x2 h[4]; } ua;
            ua.h[0] = __builtin_amdgcn_cvt_pkrtz(a0.x, a0.y);
            ua.h[1] = __builtin_amdgcn_cvt_pkrtz(a0.z, a0.w);
            ua.h[2] = __builtin_amdgcn_cvt_pkrtz(a1.x, a1.y);
            ua.h[3] = __builtin_amdgcn_cvt_pkrtz(a1.z, a1.w);
            half8_t bf = wf[c * 64 + lane];
            acc = __builtin_amdgcn_mfma_f32_32x32x16_f16(ua.v, bf, acc, 0, 0, 0);
        }

        // C/D layout (32x32): row = (r&3) + 8*(r>>2) + 4*kh, col = colgrp*32 + l31
        // Each store instr: lanes 0-31 one 128B line, lanes 32-63 another. Fully coalesced.
        float* op = out + (size_t)(m0 + 4 * kh) * N + colgrp * 32 + l31;
#pragma unroll
        for (int r = 0; r < 16; ++r) {
            op[(size_t)((r & 3) + 8 * (r >> 2)) * N] = acc[r];
        }
    }
}

extern "C" void kernel_launch(void* const* d_in, const int* in_sizes, int n_in,
                              void* d_out, int out_size, void* d_ws, size_t ws_size,
                              hipStream_t stream) {
    const float* x = (const float*)d_in[0];
    const float* W = (const float*)d_in[1];
    const float* b = (const float*)d_in[2];
    float* out = (float*)d_out;
    linear_mfma_kernel<<<GRID, 512, 0, stream>>>(x, W, b, out);
}